// Round 1
// baseline (473.501 us; speedup 1.0000x reference)
//
#include <hip/hip_runtime.h>
#include <math.h>

#define N_NODES 100000
#define N_EDGES 3200000
#define IN_DIM 128
#define HG 64

#define E0CAP 2048     // capacity for edges into node 0 (expected ~32)
#define MCAP  65536    // capacity for edges into S1 nodes (expected ~1100)

// workspace byte offsets (all multiples of 16)
#define OFF_DEG       0u          // int[N_NODES]           400000 B
#define OFF_SLOTMAP   400000u     // int[N_NODES]           400000 B
#define OFF_CNT       800000u     // int[4]: n0, nslots, m  16 B
#define OFF_EDGES0    800016u     // int[E0CAP]             8192 B
#define OFF_SLOTNODE  808208u     // int[E0CAP]             8192 B
#define OFF_MLIST     816400u     // int[MCAP]              262144 B
#define OFF_ACC       1078544u    // float[E0CAP*HG]        524288 B
#define WS_ZERO_BYTES 1602832u

__device__ __forceinline__ float dinv_of(int degv) {
    // reference: deg = indeg + 1 (self loop), dinv = 1/sqrt(deg), deg >= 1 always
    return 1.0f / sqrtf((float)(degv + 1));
}

// Pass 1: full in-degree histogram + collect srcs of edges into node 0.
__global__ void k_deg_edges0(const int* __restrict__ src, const int* __restrict__ dst,
                             int* __restrict__ deg, int* __restrict__ cnt,
                             int* __restrict__ edges0) {
    int tid = blockIdx.x * blockDim.x + threadIdx.x;
    int nth = gridDim.x * blockDim.x;
    const int4* dst4 = (const int4*)dst;
    const int n4 = N_EDGES / 4;
    for (int i = tid; i < n4; i += nth) {
        int4 dv = dst4[i];
        int ds[4] = {dv.x, dv.y, dv.z, dv.w};
#pragma unroll
        for (int k = 0; k < 4; k++) {
            atomicAdd(&deg[ds[k]], 1);
            if (ds[k] == 0) {
                int p = atomicAdd(&cnt[0], 1);
                if (p < E0CAP) edges0[p] = src[4 * i + k];
            }
        }
    }
}

// Pass 2 (1 thread): build slot map over S1 = {0} U unique srcs of edges into 0.
__global__ void k_build_slots(int* __restrict__ slotmap, int* __restrict__ cnt,
                              const int* __restrict__ edges0, int* __restrict__ slotnodes) {
    if (blockIdx.x == 0 && threadIdx.x == 0) {
        int ns = 0;
        slotmap[0] = 1; slotnodes[0] = 0; ns = 1;
        int n0 = cnt[0]; if (n0 > E0CAP) n0 = E0CAP;
        for (int i = 0; i < n0; i++) {
            int s = edges0[i];
            if (slotmap[s] == 0) {
                if (ns >= E0CAP) break;
                slotmap[s] = ns + 1;
                slotnodes[ns] = s;
                ns++;
            }
        }
        cnt[1] = ns;
    }
}

// Pass 3: find all edges whose dst is in S1.
__global__ void k_match(const int* __restrict__ dst, const int* __restrict__ slotmap,
                        int* __restrict__ cnt, int* __restrict__ mlist) {
    int tid = blockIdx.x * blockDim.x + threadIdx.x;
    int nth = gridDim.x * blockDim.x;
    const int4* dst4 = (const int4*)dst;
    const int n4 = N_EDGES / 4;
    for (int i = tid; i < n4; i += nth) {
        int4 dv = dst4[i];
        int ds[4] = {dv.x, dv.y, dv.z, dv.w};
#pragma unroll
        for (int k = 0; k < 4; k++) {
            if (slotmap[ds[k]] != 0) {
                int p = atomicAdd(&cnt[2], 1);
                if (p < MCAP) mlist[p] = 4 * i + k;
            }
        }
    }
}

// Pass 4: per matched edge (s->d), accumulate (x_s @ W1) * dinv[s]*dinv[d] into acc[slot(d)].
// One 64-thread block per edge; thread j computes output channel j.
__global__ void k_edge_contrib(const int* __restrict__ src, const int* __restrict__ dst,
                               const int* __restrict__ deg, const int* __restrict__ slotmap,
                               const int* __restrict__ cnt, const int* __restrict__ mlist,
                               const float* __restrict__ x, const float* __restrict__ W1,
                               float* __restrict__ acc) {
    int m = cnt[2]; if (m > MCAP) m = MCAP;
    int j = threadIdx.x;  // 0..63
    for (int ii = blockIdx.x; ii < m; ii += gridDim.x) {
        int e = mlist[ii];
        int s = src[e];
        int d = dst[e];
        int sl = slotmap[d] - 1;
        float w = dinv_of(deg[s]) * dinv_of(deg[d]);
        float g = 0.f;
#pragma unroll 4
        for (int k = 0; k < IN_DIM; k++) {
            g = fmaf(x[(size_t)k * N_NODES + s], W1[k * HG + j], g);
        }
        atomicAdd(&acc[sl * HG + j], g * w);
    }
}

// Pass 5: self-loop + bias + ReLU per slot, layer-2 agg at node 0, W2 matvec,
// LSTM single step (h0=c0=0), FC -> scalar.
__global__ void k_final(const float* __restrict__ x, const float* __restrict__ W1,
                        const float* __restrict__ b1, const float* __restrict__ W2,
                        const float* __restrict__ b2, const float* __restrict__ w_ih,
                        const float* __restrict__ b_ih, const float* __restrict__ b_hh,
                        const float* __restrict__ fc_w, const float* __restrict__ fc_b,
                        const int* __restrict__ deg, const int* __restrict__ slotmap,
                        const int* __restrict__ cnt, const int* __restrict__ edges0,
                        const int* __restrict__ slotnodes,
                        float* __restrict__ acc, float* __restrict__ out) {
    __shared__ float xcol[IN_DIM];
    __shared__ float agg[HG];
    __shared__ float zv[HG];
    __shared__ float gates[4 * HG];
    __shared__ float hw[HG];
    const int t = threadIdx.x;
    const int ns = cnt[1];
    int n0 = cnt[0]; if (n0 > E0CAP) n0 = E0CAP;

    // h1[slot] = relu(acc + g1(node)*dinv^2 + b1), written in place into acc
    for (int i = 0; i < ns; i++) {
        int n = slotnodes[i];
        __syncthreads();
        for (int k = t; k < IN_DIM; k += blockDim.x) xcol[k] = x[(size_t)k * N_NODES + n];
        __syncthreads();
        if (t < HG) {
            float g = 0.f;
#pragma unroll 4
            for (int k = 0; k < IN_DIM; k++) g = fmaf(xcol[k], W1[k * HG + t], g);
            float dv = dinv_of(deg[n]);
            float h = acc[i * HG + t] + g * dv * dv + b1[t];
            acc[i * HG + t] = h > 0.f ? h : 0.f;
        }
    }
    __syncthreads();

    // layer-2 aggregation at node 0 (slot 0): self loop + real edges (with multiplicity)
    float dinv0 = dinv_of(deg[0]);
    if (t < HG) {
        float a = dinv0 * dinv0 * acc[t];
        for (int i = 0; i < n0; i++) {
            int s = edges0[i];
            int sl = slotmap[s] - 1;
            a += dinv_of(deg[s]) * dinv0 * acc[sl * HG + t];
        }
        agg[t] = a;
    }
    __syncthreads();

    // z = agg @ W2 + b2   (no relu on layer 2)
    if (t < HG) {
        float zz = b2[t];
#pragma unroll 4
        for (int k = 0; k < HG; k++) zz = fmaf(agg[k], W2[k * HG + t], zz);
        zv[t] = zz;
    }
    __syncthreads();

    // gates = z @ w_ih.T + b_ih + b_hh
    if (t < 4 * HG) {
        float gt = b_ih[t] + b_hh[t];
#pragma unroll 4
        for (int j = 0; j < HG; j++) gt = fmaf(zv[j], w_ih[t * HG + j], gt);
        gates[t] = gt;
    }
    __syncthreads();

    // c = sig(i)*tanh(g); hy = sig(o)*tanh(c); y = hy @ fc_w.T + fc_b
    if (t < HG) {
        float ig = 1.f / (1.f + expf(-gates[t]));
        float gg = tanhf(gates[2 * HG + t]);
        float og = 1.f / (1.f + expf(-gates[3 * HG + t]));
        float c = ig * gg;
        float hy = og * tanhf(c);
        hw[t] = hy * fc_w[t];
    }
    __syncthreads();
    if (t == 0) {
        float y = fc_b[0];
        for (int j = 0; j < HG; j++) y += hw[j];
        out[0] = y;
    }
}

extern "C" void kernel_launch(void* const* d_in, const int* in_sizes, int n_in,
                              void* d_out, int out_size, void* d_ws, size_t ws_size,
                              hipStream_t stream) {
    const float* x    = (const float*)d_in[0];
    const int*   ei   = (const int*)d_in[1];
    const float* W1   = (const float*)d_in[2];
    const float* b1   = (const float*)d_in[3];
    const float* W2   = (const float*)d_in[4];
    const float* b2   = (const float*)d_in[5];
    const float* w_ih = (const float*)d_in[6];
    // d_in[7] = w_hh, unused (h0 = 0)
    const float* b_ih = (const float*)d_in[8];
    const float* b_hh = (const float*)d_in[9];
    const float* fc_w = (const float*)d_in[10];
    const float* fc_b = (const float*)d_in[11];
    float* out = (float*)d_out;

    const int* src = ei;
    const int* dst = ei + N_EDGES;

    char* ws = (char*)d_ws;
    int*   deg       = (int*)(ws + OFF_DEG);
    int*   slotmap   = (int*)(ws + OFF_SLOTMAP);
    int*   cnt       = (int*)(ws + OFF_CNT);
    int*   edges0    = (int*)(ws + OFF_EDGES0);
    int*   slotnodes = (int*)(ws + OFF_SLOTNODE);
    int*   mlist     = (int*)(ws + OFF_MLIST);
    float* acc       = (float*)(ws + OFF_ACC);

    hipMemsetAsync(ws, 0, WS_ZERO_BYTES, stream);

    k_deg_edges0<<<1024, 256, 0, stream>>>(src, dst, deg, cnt, edges0);
    k_build_slots<<<1, 64, 0, stream>>>(slotmap, cnt, edges0, slotnodes);
    k_match<<<1024, 256, 0, stream>>>(dst, slotmap, cnt, mlist);
    k_edge_contrib<<<512, 64, 0, stream>>>(src, dst, deg, slotmap, cnt, mlist, x, W1, acc);
    k_final<<<1, 256, 0, stream>>>(x, W1, b1, W2, b2, w_ih, b_ih, b_hh, fc_w, fc_b,
                                   deg, slotmap, cnt, edges0, slotnodes, acc, out);
}

// Round 2
// 288.193 us; speedup vs baseline: 1.6430x; 1.6430x over previous
//
#include <hip/hip_runtime.h>
#include <math.h>

#define N_NODES 100000
#define N_EDGES 3200000
#define IN_DIM 128
#define HG 64

#define E0CAP 2048     // capacity for edges into node 0 (expected ~32)
#define MCAP  65536    // capacity for edges into S1 nodes (expected ~1100)

// workspace byte offsets (all multiples of 16)
#define OFF_DEG       0u          // int[N_NODES]           400000 B
#define OFF_SLOTMAP   400000u     // int[N_NODES]           400000 B
#define OFF_CNT       800000u     // int[4]: n0, nslots, m  16 B
#define OFF_EDGES0    800016u     // int[E0CAP]             8192 B
#define OFF_SLOTNODE  808208u     // int[E0CAP]             8192 B
#define OFF_MLIST     816400u     // int[MCAP]              262144 B
#define OFF_ACC       1078544u    // float[E0CAP*HG]        524288 B
#define WS_ZERO_BYTES 1602832u

__device__ __forceinline__ float dinv_of(int degv) {
    // reference: deg = indeg + 1 (self loop), dinv = 1/sqrt(deg), always >= 1
    return 1.0f / sqrtf((float)(degv + 1));
}

// Pass 1: full in-degree histogram + collect srcs of edges into node 0.
__global__ void k_deg_edges0(const int* __restrict__ src, const int* __restrict__ dst,
                             int* __restrict__ deg, int* __restrict__ cnt,
                             int* __restrict__ edges0) {
    int tid = blockIdx.x * blockDim.x + threadIdx.x;
    int nth = gridDim.x * blockDim.x;
    const int4* dst4 = (const int4*)dst;
    const int n4 = N_EDGES / 4;
    for (int i = tid; i < n4; i += nth) {
        int4 dv = dst4[i];
        int ds[4] = {dv.x, dv.y, dv.z, dv.w};
#pragma unroll
        for (int k = 0; k < 4; k++) {
            atomicAdd(&deg[ds[k]], 1);
            if (ds[k] == 0) {
                int p = atomicAdd(&cnt[0], 1);
                if (p < E0CAP) edges0[p] = src[4 * i + k];
            }
        }
    }
}

// Pass 2: parallel slot build over S1 = {0} U unique srcs of edges into 0.
// Single block; atomicCAS dedupe, then reassign compact slot ids.
__global__ void k_build_slots(int* __restrict__ slotmap, int* __restrict__ cnt,
                              const int* __restrict__ edges0, int* __restrict__ slotnodes) {
    const int t = threadIdx.x;
    int n0 = cnt[0]; if (n0 > E0CAP) n0 = E0CAP;
    const int total = n0 + 1;  // + node 0
    for (int i = t; i < total; i += blockDim.x) {
        int s = (i == n0) ? 0 : edges0[i];
        if (atomicCAS(&slotmap[s], 0, 1) == 0) {
            int p = atomicAdd(&cnt[1], 1);
            if (p < E0CAP) slotnodes[p] = s;
        }
    }
    __syncthreads();
    int ns = cnt[1]; if (ns > E0CAP) ns = E0CAP;
    for (int i = t; i < ns; i += blockDim.x) slotmap[slotnodes[i]] = i + 1;
}

// Pass 3: find all edges whose dst is in S1.
__global__ void k_match(const int* __restrict__ dst, const int* __restrict__ slotmap,
                        int* __restrict__ cnt, int* __restrict__ mlist) {
    int tid = blockIdx.x * blockDim.x + threadIdx.x;
    int nth = gridDim.x * blockDim.x;
    const int4* dst4 = (const int4*)dst;
    const int n4 = N_EDGES / 4;
    for (int i = tid; i < n4; i += nth) {
        int4 dv = dst4[i];
        int ds[4] = {dv.x, dv.y, dv.z, dv.w};
#pragma unroll
        for (int k = 0; k < 4; k++) {
            if (slotmap[ds[k]] != 0) {
                int p = atomicAdd(&cnt[2], 1);
                if (p < MCAP) mlist[p] = 4 * i + k;
            }
        }
    }
}

// Pass 4: real edges (s->d): acc[slot(d)] += (x_s @ W1) * dinv[s]*dinv[d]
//         virtual self-loop edges (n->n): acc[slot(n)] += (x_n @ W1) * dinv[n]^2
// One 64-thread block per (virtual) edge; thread j = output channel.
__global__ void k_edge_contrib(const int* __restrict__ src, const int* __restrict__ dst,
                               const int* __restrict__ deg, const int* __restrict__ slotmap,
                               const int* __restrict__ cnt, const int* __restrict__ mlist,
                               const int* __restrict__ slotnodes,
                               const float* __restrict__ x, const float* __restrict__ W1,
                               float* __restrict__ acc) {
    int m = cnt[2]; if (m > MCAP) m = MCAP;
    int ns = cnt[1]; if (ns > E0CAP) ns = E0CAP;
    const int total = m + ns;
    const int j = threadIdx.x;  // 0..63
    for (int ii = blockIdx.x; ii < total; ii += gridDim.x) {
        int s, sl;
        float w;
        if (ii < m) {
            int e = mlist[ii];
            s = src[e];
            int d = dst[e];
            sl = slotmap[d] - 1;
            w = dinv_of(deg[s]) * dinv_of(deg[d]);
        } else {
            sl = ii - m;
            s = slotnodes[sl];
            float dv = dinv_of(deg[s]);
            w = dv * dv;
        }
        float g = 0.f;
#pragma unroll 8
        for (int k = 0; k < IN_DIM; k++) {
            g = fmaf(x[(size_t)k * N_NODES + s], W1[k * HG + j], g);
        }
        atomicAdd(&acc[sl * HG + j], g * w);
    }
}

// Pass 5: layer-2 agg at node 0 (relu+bias applied inline), W2 matvec,
// LSTM single step (h0=c0=0), FC -> scalar. Single block, latency-tolerant.
#define CHUNK 256
__global__ void k_final(const float* __restrict__ b1, const float* __restrict__ W2,
                        const float* __restrict__ b2, const float* __restrict__ w_ih,
                        const float* __restrict__ b_ih, const float* __restrict__ b_hh,
                        const float* __restrict__ fc_w, const float* __restrict__ fc_b,
                        const int* __restrict__ deg, const int* __restrict__ slotmap,
                        const int* __restrict__ cnt, const int* __restrict__ edges0,
                        const float* __restrict__ acc, float* __restrict__ out) {
    __shared__ int   sh_sl[CHUNK];
    __shared__ float sh_w[CHUNK];
    __shared__ float partial[4][HG];
    __shared__ float agg[HG];
    __shared__ float zv[HG];
    __shared__ float gates[4 * HG];
    __shared__ float hw[HG];
    const int t = threadIdx.x;
    const int ch = t & (HG - 1);   // channel 0..63
    const int grp = t >> 6;        // group 0..3
    int n0 = cnt[0]; if (n0 > E0CAP) n0 = E0CAP;

    const float dinv0 = dinv_of(deg[0]);
    const float bch = b1[ch];

    float a = 0.f;
    for (int base = 0; base < n0; base += CHUNK) {
        int cn = n0 - base; if (cn > CHUNK) cn = CHUNK;
        __syncthreads();
        if (t < cn) {
            int s = edges0[base + t];
            sh_sl[t] = slotmap[s] - 1;
            sh_w[t] = dinv_of(deg[s]) * dinv0;
        }
        __syncthreads();
        for (int i = grp; i < cn; i += 4) {
            float h = acc[sh_sl[i] * HG + ch] + bch;
            a = fmaf(sh_w[i], (h > 0.f ? h : 0.f), a);
        }
    }
    partial[grp][ch] = a;
    __syncthreads();
    if (t < HG) {
        int sl0 = slotmap[0] - 1;
        float h0 = acc[sl0 * HG + t] + b1[t];
        float s = dinv0 * dinv0 * (h0 > 0.f ? h0 : 0.f);
        s += partial[0][t] + partial[1][t] + partial[2][t] + partial[3][t];
        agg[t] = s;
    }
    __syncthreads();

    // z = agg @ W2 + b2 (no relu on layer 2)
    if (t < HG) {
        float zz = b2[t];
#pragma unroll 8
        for (int k = 0; k < HG; k++) zz = fmaf(agg[k], W2[k * HG + t], zz);
        zv[t] = zz;
    }
    __syncthreads();

    // gates = z @ w_ih.T + b_ih + b_hh (all 256 threads)
    {
        float gt = b_ih[t] + b_hh[t];
#pragma unroll 8
        for (int j = 0; j < HG; j++) gt = fmaf(zv[j], w_ih[t * HG + j], gt);
        gates[t] = gt;
    }
    __syncthreads();

    // c = sig(i)*tanh(g); hy = sig(o)*tanh(c); y = hy @ fc_w.T + fc_b
    if (t < HG) {
        float ig = 1.f / (1.f + expf(-gates[t]));
        float gg = tanhf(gates[2 * HG + t]);
        float og = 1.f / (1.f + expf(-gates[3 * HG + t]));
        float c = ig * gg;
        float hy = og * tanhf(c);
        hw[t] = hy * fc_w[t];
    }
    __syncthreads();
    if (t == 0) {
        float y = fc_b[0];
        for (int j = 0; j < HG; j++) y += hw[j];
        out[0] = y;
    }
}

extern "C" void kernel_launch(void* const* d_in, const int* in_sizes, int n_in,
                              void* d_out, int out_size, void* d_ws, size_t ws_size,
                              hipStream_t stream) {
    const float* x    = (const float*)d_in[0];
    const int*   ei   = (const int*)d_in[1];
    const float* W1   = (const float*)d_in[2];
    const float* b1   = (const float*)d_in[3];
    const float* W2   = (const float*)d_in[4];
    const float* b2   = (const float*)d_in[5];
    const float* w_ih = (const float*)d_in[6];
    // d_in[7] = w_hh, unused (h0 = 0)
    const float* b_ih = (const float*)d_in[8];
    const float* b_hh = (const float*)d_in[9];
    const float* fc_w = (const float*)d_in[10];
    const float* fc_b = (const float*)d_in[11];
    float* out = (float*)d_out;

    const int* src = ei;
    const int* dst = ei + N_EDGES;

    char* ws = (char*)d_ws;
    int*   deg       = (int*)(ws + OFF_DEG);
    int*   slotmap   = (int*)(ws + OFF_SLOTMAP);
    int*   cnt       = (int*)(ws + OFF_CNT);
    int*   edges0    = (int*)(ws + OFF_EDGES0);
    int*   slotnodes = (int*)(ws + OFF_SLOTNODE);
    int*   mlist     = (int*)(ws + OFF_MLIST);
    float* acc       = (float*)(ws + OFF_ACC);

    hipMemsetAsync(ws, 0, WS_ZERO_BYTES, stream);

    k_deg_edges0<<<1024, 256, 0, stream>>>(src, dst, deg, cnt, edges0);
    k_build_slots<<<1, 256, 0, stream>>>(slotmap, cnt, edges0, slotnodes);
    k_match<<<1024, 256, 0, stream>>>(dst, slotmap, cnt, mlist);
    k_edge_contrib<<<1024, 64, 0, stream>>>(src, dst, deg, slotmap, cnt, mlist,
                                            slotnodes, x, W1, acc);
    k_final<<<1, 256, 0, stream>>>(b1, W2, b2, w_ih, b_ih, b_hh, fc_w, fc_b,
                                   deg, slotmap, cnt, edges0, acc, out);
}

// Round 3
// 184.635 us; speedup vs baseline: 2.5645x; 1.5609x over previous
//
#include <hip/hip_runtime.h>
#include <math.h>

#define N_NODES 100000
#define N_EDGES 3200000
#define IN_DIM 128
#define HG 64

#define E0CAP 2048     // capacity for edges into node 0 (expected ~32)
#define MCAP  65536    // capacity for edges into S1 nodes (expected ~1100)

#define NEED_BIT 0x10000
#define SLOT_MASK 0xFFFF

// workspace byte offsets; [0, WS_ZERO_BYTES) must be zeroed each launch
#define OFF_DEG       0u          // int[N_NODES]           400000 B
#define OFF_SLOTMAP   400000u     // int[N_NODES]           400000 B (low16: slot+1, bit16: need-deg)
#define OFF_CNT       800000u     // int[4]: n0, ns, m      16 B
#define OFF_ACC       800016u     // float[E0CAP*HG]        524288 B
#define WS_ZERO_BYTES 1324304u
#define OFF_EDGES0    1324304u    // int[E0CAP]
#define OFF_SLOTNODE  1332496u    // int[E0CAP]
#define OFF_MLIST     1340688u    // int[MCAP]

__device__ __forceinline__ float dinv_of(int degv) {
    // reference: deg = indeg + 1 (self loop), dinv = 1/sqrt(deg), always >= 1
    return 1.0f / sqrtf((float)(degv + 1));
}

// Pass 1: scan dst for edges into node 0; collect their srcs. No histogram.
__global__ void k_scan0(const int* __restrict__ src, const int* __restrict__ dst,
                        int* __restrict__ cnt, int* __restrict__ edges0) {
    int tid = blockIdx.x * blockDim.x + threadIdx.x;
    int nth = gridDim.x * blockDim.x;
    const int4* dst4 = (const int4*)dst;
    const int n4 = N_EDGES / 4;
    for (int i = tid; i < n4; i += nth) {
        int4 dv = dst4[i];
        int ds[4] = {dv.x, dv.y, dv.z, dv.w};
#pragma unroll
        for (int k = 0; k < 4; k++) {
            if (ds[k] == 0) {
                int p = atomicAdd(&cnt[0], 1);
                if (p < E0CAP) edges0[p] = src[4 * i + k];
            }
        }
    }
}

// Pass 2: parallel slot build over S1 = {0} U unique srcs of edges into 0.
__global__ void k_build_slots(int* __restrict__ slotmap, int* __restrict__ cnt,
                              const int* __restrict__ edges0, int* __restrict__ slotnodes) {
    const int t = threadIdx.x;
    int n0 = cnt[0]; if (n0 > E0CAP) n0 = E0CAP;
    const int total = n0 + 1;  // + node 0
    for (int i = t; i < total; i += blockDim.x) {
        int s = (i == n0) ? 0 : edges0[i];
        if (atomicCAS(&slotmap[s], 0, 1) == 0) {
            int p = atomicAdd(&cnt[1], 1);
            if (p < E0CAP) slotnodes[p] = s;
        }
    }
    __syncthreads();
    int ns = cnt[1]; if (ns > E0CAP) ns = E0CAP;
    for (int i = t; i < ns; i += blockDim.x) slotmap[slotnodes[i]] = i + 1;
}

// Pass 3: find edges whose dst is in S1; mark their srcs as degree-needed.
__global__ void k_match(const int* __restrict__ src, const int* __restrict__ dst,
                        int* __restrict__ slotmap, int* __restrict__ cnt,
                        int* __restrict__ mlist) {
    int tid = blockIdx.x * blockDim.x + threadIdx.x;
    int nth = gridDim.x * blockDim.x;
    const int4* dst4 = (const int4*)dst;
    const int n4 = N_EDGES / 4;
    for (int i = tid; i < n4; i += nth) {
        int4 dv = dst4[i];
        int ds[4] = {dv.x, dv.y, dv.z, dv.w};
#pragma unroll
        for (int k = 0; k < 4; k++) {
            if ((slotmap[ds[k]] & SLOT_MASK) != 0) {
                int e = 4 * i + k;
                int p = atomicAdd(&cnt[2], 1);
                if (p < MCAP) mlist[p] = e;
                atomicOr(&slotmap[src[e]], NEED_BIT);
            }
        }
    }
}

// Pass 4: filtered in-degree: count only nodes whose degree will be consumed
// (S1 members or srcs of matched edges). ~37k atomics instead of 3.2M.
__global__ void k_deg_need(const int* __restrict__ dst, const int* __restrict__ slotmap,
                           int* __restrict__ deg) {
    int tid = blockIdx.x * blockDim.x + threadIdx.x;
    int nth = gridDim.x * blockDim.x;
    const int4* dst4 = (const int4*)dst;
    const int n4 = N_EDGES / 4;
    for (int i = tid; i < n4; i += nth) {
        int4 dv = dst4[i];
        int ds[4] = {dv.x, dv.y, dv.z, dv.w};
#pragma unroll
        for (int k = 0; k < 4; k++) {
            if (slotmap[ds[k]] != 0) atomicAdd(&deg[ds[k]], 1);
        }
    }
}

// Pass 5: real edges (s->d): acc[slot(d)] += (x_s @ W1) * dinv[s]*dinv[d]
//         virtual self-loop edges (n->n): acc[slot(n)] += (x_n @ W1) * dinv[n]^2
__global__ void k_edge_contrib(const int* __restrict__ src, const int* __restrict__ dst,
                               const int* __restrict__ deg, const int* __restrict__ slotmap,
                               const int* __restrict__ cnt, const int* __restrict__ mlist,
                               const int* __restrict__ slotnodes,
                               const float* __restrict__ x, const float* __restrict__ W1,
                               float* __restrict__ acc) {
    int m = cnt[2]; if (m > MCAP) m = MCAP;
    int ns = cnt[1]; if (ns > E0CAP) ns = E0CAP;
    const int total = m + ns;
    const int j = threadIdx.x;  // 0..63
    for (int ii = blockIdx.x; ii < total; ii += gridDim.x) {
        int s, sl;
        float w;
        if (ii < m) {
            int e = mlist[ii];
            s = src[e];
            int d = dst[e];
            sl = (slotmap[d] & SLOT_MASK) - 1;
            w = dinv_of(deg[s]) * dinv_of(deg[d]);
        } else {
            sl = ii - m;
            s = slotnodes[sl];
            float dv = dinv_of(deg[s]);
            w = dv * dv;
        }
        float g = 0.f;
#pragma unroll 8
        for (int k = 0; k < IN_DIM; k++) {
            g = fmaf(x[(size_t)k * N_NODES + s], W1[k * HG + j], g);
        }
        atomicAdd(&acc[sl * HG + j], g * w);
    }
}

// Pass 6: layer-2 agg at node 0 (relu+bias inline), W2 matvec, LSTM, FC.
#define CHUNK 256
__global__ void k_final(const float* __restrict__ b1, const float* __restrict__ W2,
                        const float* __restrict__ b2, const float* __restrict__ w_ih,
                        const float* __restrict__ b_ih, const float* __restrict__ b_hh,
                        const float* __restrict__ fc_w, const float* __restrict__ fc_b,
                        const int* __restrict__ deg, const int* __restrict__ slotmap,
                        const int* __restrict__ cnt, const int* __restrict__ edges0,
                        const float* __restrict__ acc, float* __restrict__ out) {
    __shared__ int   sh_sl[CHUNK];
    __shared__ float sh_w[CHUNK];
    __shared__ float partial[4][HG];
    __shared__ float agg[HG];
    __shared__ float zv[HG];
    __shared__ float gates[4 * HG];
    __shared__ float hw[HG];
    const int t = threadIdx.x;
    const int ch = t & (HG - 1);
    const int grp = t >> 6;
    int n0 = cnt[0]; if (n0 > E0CAP) n0 = E0CAP;

    const float dinv0 = dinv_of(deg[0]);
    const float bch = b1[ch];

    float a = 0.f;
    for (int base = 0; base < n0; base += CHUNK) {
        int cn = n0 - base; if (cn > CHUNK) cn = CHUNK;
        __syncthreads();
        if (t < cn) {
            int s = edges0[base + t];
            sh_sl[t] = (slotmap[s] & SLOT_MASK) - 1;
            sh_w[t] = dinv_of(deg[s]) * dinv0;
        }
        __syncthreads();
        for (int i = grp; i < cn; i += 4) {
            float h = acc[sh_sl[i] * HG + ch] + bch;
            a = fmaf(sh_w[i], (h > 0.f ? h : 0.f), a);
        }
    }
    partial[grp][ch] = a;
    __syncthreads();
    if (t < HG) {
        int sl0 = (slotmap[0] & SLOT_MASK) - 1;
        float h0 = acc[sl0 * HG + t] + b1[t];
        float s = dinv0 * dinv0 * (h0 > 0.f ? h0 : 0.f);
        s += partial[0][t] + partial[1][t] + partial[2][t] + partial[3][t];
        agg[t] = s;
    }
    __syncthreads();

    if (t < HG) {
        float zz = b2[t];
#pragma unroll 8
        for (int k = 0; k < HG; k++) zz = fmaf(agg[k], W2[k * HG + t], zz);
        zv[t] = zz;
    }
    __syncthreads();

    {
        float gt = b_ih[t] + b_hh[t];
#pragma unroll 8
        for (int j = 0; j < HG; j++) gt = fmaf(zv[j], w_ih[t * HG + j], gt);
        gates[t] = gt;
    }
    __syncthreads();

    if (t < HG) {
        float ig = 1.f / (1.f + expf(-gates[t]));
        float gg = tanhf(gates[2 * HG + t]);
        float og = 1.f / (1.f + expf(-gates[3 * HG + t]));
        float c = ig * gg;
        float hy = og * tanhf(c);
        hw[t] = hy * fc_w[t];
    }
    __syncthreads();
    if (t == 0) {
        float y = fc_b[0];
        for (int j = 0; j < HG; j++) y += hw[j];
        out[0] = y;
    }
}

extern "C" void kernel_launch(void* const* d_in, const int* in_sizes, int n_in,
                              void* d_out, int out_size, void* d_ws, size_t ws_size,
                              hipStream_t stream) {
    const float* x    = (const float*)d_in[0];
    const int*   ei   = (const int*)d_in[1];
    const float* W1   = (const float*)d_in[2];
    const float* b1   = (const float*)d_in[3];
    const float* W2   = (const float*)d_in[4];
    const float* b2   = (const float*)d_in[5];
    const float* w_ih = (const float*)d_in[6];
    // d_in[7] = w_hh, unused (h0 = 0)
    const float* b_ih = (const float*)d_in[8];
    const float* b_hh = (const float*)d_in[9];
    const float* fc_w = (const float*)d_in[10];
    const float* fc_b = (const float*)d_in[11];
    float* out = (float*)d_out;

    const int* src = ei;
    const int* dst = ei + N_EDGES;

    char* ws = (char*)d_ws;
    int*   deg       = (int*)(ws + OFF_DEG);
    int*   slotmap   = (int*)(ws + OFF_SLOTMAP);
    int*   cnt       = (int*)(ws + OFF_CNT);
    float* acc       = (float*)(ws + OFF_ACC);
    int*   edges0    = (int*)(ws + OFF_EDGES0);
    int*   slotnodes = (int*)(ws + OFF_SLOTNODE);
    int*   mlist     = (int*)(ws + OFF_MLIST);

    hipMemsetAsync(ws, 0, WS_ZERO_BYTES, stream);

    k_scan0<<<1024, 256, 0, stream>>>(src, dst, cnt, edges0);
    k_build_slots<<<1, 256, 0, stream>>>(slotmap, cnt, edges0, slotnodes);
    k_match<<<1024, 256, 0, stream>>>(src, dst, slotmap, cnt, mlist);
    k_deg_need<<<1024, 256, 0, stream>>>(dst, slotmap, deg);
    k_edge_contrib<<<1024, 64, 0, stream>>>(src, dst, deg, slotmap, cnt, mlist,
                                            slotnodes, x, W1, acc);
    k_final<<<1, 256, 0, stream>>>(b1, W2, b2, w_ih, b_ih, b_hh, fc_w, fc_b,
                                   deg, slotmap, cnt, edges0, acc, out);
}